// Round 11
// baseline (3511.248 us; speedup 1.0000x reference)
//
#include <hip/hip_runtime.h>
#include <hip/hip_bf16.h>
#include <math.h>

// Fused LM-head cross-entropy: loss = mean_valid( logsumexp(x@W^T) - logit[y] )
// N=4096 tokens, H=4096 hidden, V=128000 vocab.
//
// Round 11: MX-fp8 (identity scales, validated R10) ported to the m97/m148
// 128x128 single-buffered 2-barrier structure: 34KB LDS -> 4 blocks/CU, so
// independent blocks' barriers desynchronize and staging hides under other
// blocks' MFMA (cross-block overlap instead of intra-block scheduling).

#define N_ROWS 4096
#define H_DIM  4096
#define V_DIM  128000
#define BM 128
#define BN 128
#define NT_N (N_ROWS / BM)      // 32
#define NT_V (V_DIM / BN)       // 1000
#define NKT  (H_DIM / 128)      // 32 K-tiles (128 fp8 elems each)
#define IGNORE_INDEX (-100)

typedef __attribute__((ext_vector_type(4))) int   i32x4;
typedef __attribute__((ext_vector_type(8))) int   i32x8;
typedef __attribute__((ext_vector_type(4))) float f32x4;
typedef __attribute__((ext_vector_type(16))) float f32x16;
typedef const __attribute__((address_space(1))) unsigned int* gas1_u32;
typedef __attribute__((address_space(3))) unsigned int* las3_u32;

// ---------------- exact f32 -> e4m3fn (OCP), RNE, saturating ----------------
__device__ __forceinline__ unsigned f2e4m3(float f) {
    unsigned u = __float_as_uint(f);
    unsigned s = (u >> 24) & 0x80u;
    float af = __uint_as_float(u & 0x7FFFFFFFu);
    unsigned code;
    if (af >= 0.015625f) {                       // normal range [2^-6, 448]
        if (af > 448.f) af = 448.f;
        unsigned v = __float_as_uint(af);
        v += 0x7FFFFu + ((v >> 20) & 1u);        // RNE to 3 mantissa bits
        unsigned m3 = (v >> 20) & 7u;
        int E = (int)(v >> 23) - 127;
        if (E > 8) { E = 8; m3 = 6u; }           // clamp to 448
        code = (unsigned)((E + 7) << 3) | m3;
    } else {                                      // subnormal: m * 2^-9
        code = (unsigned)rintf(af * 512.0f);     // 0..8 (8 -> 2^-6 seamlessly)
    }
    return s | code;
}

__global__ void cvt_f32_fp8_kernel(const float* __restrict__ in,
                                   unsigned char* __restrict__ out, size_t n, float scale)
{
    size_t i = ((size_t)blockIdx.x * blockDim.x + threadIdx.x) * 8;
    size_t stride = (size_t)gridDim.x * blockDim.x * 8;
    for (; i < n; i += stride) {
        f32x4 a = *(const f32x4*)(in + i);
        f32x4 b = *(const f32x4*)(in + i + 4);
        unsigned long long o;
        o  = (unsigned long long)f2e4m3(a.x * scale);
        o |= (unsigned long long)f2e4m3(a.y * scale) << 8;
        o |= (unsigned long long)f2e4m3(a.z * scale) << 16;
        o |= (unsigned long long)f2e4m3(a.w * scale) << 24;
        o |= (unsigned long long)f2e4m3(b.x * scale) << 32;
        o |= (unsigned long long)f2e4m3(b.y * scale) << 40;
        o |= (unsigned long long)f2e4m3(b.z * scale) << 48;
        o |= (unsigned long long)f2e4m3(b.w * scale) << 56;
        *(unsigned long long*)(out + i) = o;
    }
}

#define SCL1 ((int)0x7F7F7F7F)   // E8M0 127 = 2^0 in every byte (identity)

// 32B fragment read: low 16B at off, high 16B at off^16 (kb is 32-aligned so
// the XOR swizzle preserves k-ascending byte order across the pair).
__device__ __forceinline__ i32x8 rd32(const char* base, int off) {
    i32x8 r;
    *(i32x4*)&r       = *(const i32x4*)(base + off);
    *((i32x4*)&r + 1) = *(const i32x4*)(base + (off ^ 16));
    return r;
}

// ------------------- 128^2 single-buffered MX-fp8 GEMM -------------------
__global__ __launch_bounds__(256, 4)
void lmce_gemm128_kernel(const unsigned char* __restrict__ Xq, const unsigned char* __restrict__ Wq,
                         float* __restrict__ pm, float* __restrict__ pl)
{
    __shared__ __align__(16) char lsA[128 * 128];   // 16KB: [128 rows][128 k-bytes]
    __shared__ __align__(16) char lsB[128 * 128];   // 16KB
    __shared__ float red_m[2][BM];
    __shared__ float red_l[2][BM];

    // bijective XCD swizzle: nwg = 32000, divisible by 8
    const int nwg = NT_N * NT_V;
    int orig = blockIdx.x;
    int wg = (orig & 7) * (nwg >> 3) + (orig >> 3);
    int vtile = wg / NT_N;
    int ntile = wg - vtile * NT_N;

    int tid  = threadIdx.x;
    int lane = tid & 63;
    int w    = tid >> 6;          // 0..3
    int wrow = w >> 1;            // 0..1 : 64-row half of A
    int wcol = w & 1;             // 0..1 : 64-row strip of B (output cols)
    int l31  = lane & 31;
    int kb   = (lane >> 5) * 32;  // k-byte base within a 64-elem step

    // staging source: instr j covers LDS bytes [j*4096 + tid*16); source col
    // pre-swizzled with the same XOR the reads use.
    const char* gA[4];
    const char* gB[4];
    #pragma unroll
    for (int j = 0; j < 4; ++j) {
        int o    = j * 4096 + tid * 16;
        int row  = o >> 7;                       // 128B per k-row
        int colb = (o & 127) ^ ((row & 7) << 4);
        gA[j] = (const char*)Xq + (size_t)(ntile * BM + row) * 4096 + colb;
        gB[j] = (const char*)Wq + (size_t)(vtile * BN + row) * 4096 + colb;
    }

    // swizzled ds_read offsets
    int offA[2][2], offB[2][2];
    #pragma unroll
    for (int mi = 0; mi < 2; ++mi)
        #pragma unroll
        for (int ks = 0; ks < 2; ++ks) {
            int rowA = wrow * 64 + mi * 32 + l31;
            offA[mi][ks] = rowA * 128 + ((kb + ks * 64) ^ ((rowA & 7) << 4));
            int rowB = wcol * 64 + mi * 32 + l31;
            offB[mi][ks] = rowB * 128 + ((kb + ks * 64) ^ ((rowB & 7) << 4));
        }

    f32x16 acc[2][2];
    #pragma unroll
    for (int i = 0; i < 2; ++i)
        #pragma unroll
        for (int j = 0; j < 2; ++j)
            #pragma unroll
            for (int r = 0; r < 16; ++r)
                acc[i][j][r] = 0.f;

    for (int kt = 0; kt < NKT; ++kt) {
        size_t ko = (size_t)kt * 128;
        #pragma unroll
        for (int j = 0; j < 4; ++j) {
            __builtin_amdgcn_global_load_lds((gas1_u32)(gA[j] + ko),
                                             (las3_u32)(lsA + j * 4096 + tid * 16), 16, 0, 0);
            __builtin_amdgcn_global_load_lds((gas1_u32)(gB[j] + ko),
                                             (las3_u32)(lsB + j * 4096 + tid * 16), 16, 0, 0);
        }
        __syncthreads();   // drains vmcnt(0): tile ready

        i32x8 bF[2][2];
        #pragma unroll
        for (int ni = 0; ni < 2; ++ni)
            #pragma unroll
            for (int ks = 0; ks < 2; ++ks)
                bF[ni][ks] = rd32(lsB, offB[ni][ks]);
        #pragma unroll
        for (int mi = 0; mi < 2; ++mi) {
            i32x8 a0 = rd32(lsA, offA[mi][0]);
            i32x8 a1 = rd32(lsA, offA[mi][1]);
            #pragma unroll
            for (int ni = 0; ni < 2; ++ni) {
                acc[mi][ni] = __builtin_amdgcn_mfma_scale_f32_32x32x64_f8f6f4(
                    a0, bF[ni][0], acc[mi][ni], 0, 0, 0, SCL1, 0, SCL1);
                acc[mi][ni] = __builtin_amdgcn_mfma_scale_f32_32x32x64_f8f6f4(
                    a1, bF[ni][1], acc[mi][ni], 0, 0, 0, SCL1, 0, SCL1);
            }
        }
        __syncthreads();   // all waves done reading before next overwrite
    }

    // Epilogue: per-row max and sumexp over this block's 128 cols.
    // 32x32 C/D layout: col = lane&31, row = (r&3) + 8*(r>>2) + 4*(lane>>5).
    // Unscale logits by 2^-6 (W was stored x64) -- exact power of two.
    const float inv64 = 0.015625f;
    #pragma unroll
    for (int mi = 0; mi < 2; ++mi) {
        #pragma unroll
        for (int r = 0; r < 16; ++r) {
            float v0 = acc[mi][0][r] * inv64;
            float v1 = acc[mi][1][r] * inv64;
            float mx = fmaxf(v0, v1);
            #pragma unroll
            for (int s = 1; s < 32; s <<= 1)
                mx = fmaxf(mx, __shfl_xor(mx, s, 64));
            float se = __expf(v0 - mx) + __expf(v1 - mx);
            #pragma unroll
            for (int s = 1; s < 32; s <<= 1)
                se += __shfl_xor(se, s, 64);
            if (l31 == 0) {
                int rloc = wrow * 64 + mi * 32 + (r & 3) + 8 * (r >> 2) + 4 * (lane >> 5);
                red_m[wcol][rloc] = mx;
                red_l[wcol][rloc] = se;
            }
        }
    }
    __syncthreads();
    if (tid < BM) {
        float m0 = red_m[0][tid], m1 = red_m[1][tid];
        float l0 = red_l[0][tid], l1 = red_l[1][tid];
        float mm = fmaxf(m0, m1);
        float ll = l0 * __expf(m0 - mm) + l1 * __expf(m1 - mm);
        size_t idx = (size_t)vtile * N_ROWS + (size_t)(ntile * BM + tid);
        pm[idx] = mm;
        pl[idx] = ll;
    }
}

// tgt[row] = dot(x[row], W[y[row]]) in fp32 (exact vs reference)
__global__ void lmce_tgt_kernel(const float* __restrict__ X, const float* __restrict__ W,
                                const int* __restrict__ y, float* __restrict__ tgt)
{
    int row = blockIdx.x;
    int tid = threadIdx.x;
    int yv = y[row];
    float s = 0.f;
    if (yv >= 0 && yv < V_DIM) {
        const float* xr = X + (size_t)row * H_DIM;
        const float* wrow = W + (size_t)yv * H_DIM;
        #pragma unroll
        for (int j = 0; j < 4; ++j) {
            int idx = (tid + j * 256) * 4;
            f32x4 a = *(const f32x4*)(xr + idx);
            f32x4 b = *(const f32x4*)(wrow + idx);
            s += a.x * b.x + a.y * b.y + a.z * b.z + a.w * b.w;
        }
    }
    #pragma unroll
    for (int sh = 1; sh < 64; sh <<= 1) s += __shfl_xor(s, sh, 64);
    __shared__ float sred[4];
    if ((tid & 63) == 0) sred[tid >> 6] = s;
    __syncthreads();
    if (tid == 0) tgt[row] = sred[0] + sred[1] + sred[2] + sred[3];
}

// merge NT_V per-vtile (m,l) partials per row -> lse[row]
__global__ void lmce_lse_kernel(const float* __restrict__ pm, const float* __restrict__ pl,
                                float* __restrict__ lse)
{
    int tid = threadIdx.x;
    int row = blockIdx.x * 64 + (tid & 63);
    int part = tid >> 6;               // 0..3, each scans NT_V/4 = 250 vtiles
    const int per = NT_V / 4;
    float m = -INFINITY, l = 0.f;
    for (int vt = part * per; vt < (part + 1) * per; ++vt) {
        size_t idx = (size_t)vt * N_ROWS + row;
        float m2 = pm[idx], l2 = pl[idx];
        float mm = fmaxf(m, m2);
        l = l * __expf(m - mm) + l2 * __expf(m2 - mm);
        m = mm;
    }
    __shared__ float sm[4][64], sl[4][64];
    sm[part][tid & 63] = m;
    sl[part][tid & 63] = l;
    __syncthreads();
    if (tid < 64) {
        float M = sm[0][tid], L = sl[0][tid];
        #pragma unroll
        for (int p = 1; p < 4; ++p) {
            float m2 = sm[p][tid], l2 = sl[p][tid];
            float mm = fmaxf(M, m2);
            L = L * __expf(M - mm) + l2 * __expf(m2 - mm);
            M = mm;
        }
        lse[blockIdx.x * 64 + tid] = M + logf(L);
    }
}

__global__ void lmce_final_kernel(const float* __restrict__ lse, const float* __restrict__ tgt,
                                  const int* __restrict__ y, float* __restrict__ out)
{
    int tid = threadIdx.x;
    float s = 0.f, c = 0.f;
    for (int i = tid; i < N_ROWS; i += 256) {
        if (y[i] != IGNORE_INDEX) {
            s += lse[i] - tgt[i];
            c += 1.f;
        }
    }
    #pragma unroll
    for (int sh = 1; sh < 64; sh <<= 1) {
        s += __shfl_xor(s, sh, 64);
        c += __shfl_xor(c, sh, 64);
    }
    __shared__ float ss[4], cc[4];
    if ((tid & 63) == 0) { ss[tid >> 6] = s; cc[tid >> 6] = c; }
    __syncthreads();
    if (tid == 0) {
        float S = ss[0] + ss[1] + ss[2] + ss[3];
        float C = cc[0] + cc[1] + cc[2] + cc[3];
        out[0] = S / fmaxf(C, 1.f);
    }
}

extern "C" void kernel_launch(void* const* d_in, const int* in_sizes, int n_in,
                              void* d_out, int out_size, void* d_ws, size_t ws_size,
                              hipStream_t stream)
{
    const float* X = (const float*)d_in[0];   // [4096, 4096] fp32
    const int*   y = (const int*)d_in[1];     // [4096] labels
    const float* W = (const float*)d_in[2];   // [128000, 4096] fp32
    float* out = (float*)d_out;

    char* ws = (char*)d_ws;
    const size_t OFF_PL  = 16384000;
    const size_t OFF_TGT = 32768000;
    const size_t OFF_LSE = 32784384;
    const size_t OFF_XQ  = 32800768;                 // 16 MB fp8 X
    const size_t OFF_WQ  = OFF_XQ + 16777216;        // 512 MB fp8 W (x64 scaled)

    float* pm  = (float*)ws;
    float* pl  = (float*)(ws + OFF_PL);
    float* tgt = (float*)(ws + OFF_TGT);
    float* lse = (float*)(ws + OFF_LSE);
    unsigned char* Xq = (unsigned char*)(ws + OFF_XQ);
    unsigned char* Wq = (unsigned char*)(ws + OFF_WQ);

    cvt_f32_fp8_kernel<<<4096, 256, 0, stream>>>(W, Wq, (size_t)V_DIM * H_DIM, 64.0f);
    cvt_f32_fp8_kernel<<<512, 256, 0, stream>>>(X, Xq, (size_t)N_ROWS * H_DIM, 1.0f);
    lmce_gemm128_kernel<<<NT_N * NT_V, 256, 0, stream>>>(Xq, Wq, pm, pl);
    lmce_tgt_kernel<<<N_ROWS, 256, 0, stream>>>(X, W, y, tgt);
    lmce_lse_kernel<<<N_ROWS / 64, 256, 0, stream>>>(pm, pl, lse);
    lmce_final_kernel<<<1, 256, 0, stream>>>(lse, tgt, y, out);
}